// Round 2
// baseline (2711.161 us; speedup 1.0000x reference)
//
#include <hip/hip_runtime.h>

#define NATOMS 50000
#define FDIM   128
#define EXDIM  64
#define NEDGE  500000
#define NPAIR  14

typedef _Float16 v8h __attribute__((ext_vector_type(8)));
typedef _Float16 v4h __attribute__((ext_vector_type(4)));
typedef float    v4f __attribute__((ext_vector_type(4)));

// Pair visiting order chosen to minimize segment reloads:
// steps: k0(0,0) k1(0,1) k4(0,2) | k5(1,2) k6(1,2) k2(1,1) k3(1,1) |
//        k12(3,1) k11(3,0) k10(3,3) k13(3,2) | k7(2,2) k8(2,2) k9(2,2)
// g loads: 4 (one per i), h loads: 7, ex: 1.  Only step 0 loads both g and h.
__constant__ int cK[14]  = {0,1,4,5,6,2,3,12,11,10,13,7,8,9};
__constant__ int cI[14]  = {0,0,0,1,1,1,1,3,3,3,3,2,2,2};
__constant__ int cJ[14]  = {0,1,2,2,2,1,1,1,0,3,2,2,2,2};
__constant__ int cLG[14] = {1,0,0,1,0,0,0,1,0,0,0,1,0,0};
__constant__ int cLH[14] = {1,1,1,0,0,1,0,0,1,1,1,0,0,0};

// W1 (14,320,256) fp32 -> W1T fp16 in MFMA-B-fragment tile order:
// W1T[k14][nt(16)][kc(10)][quad(4)][col(16)][j(8)]
//   element = W1[k14][kc*32+quad*8+j][nt*16+col]
__global__ __launch_bounds__(256) void prep_w1(const float* __restrict__ W1,
                                               _Float16* __restrict__ W1T) {
    int tid = blockIdx.x * 256 + threadIdx.x;
    if (tid >= 14*320*256) return;
    int n   = tid & 255;
    int t   = tid >> 8;
    int kk  = t % 320;
    int k14 = t / 320;
    float v = W1[tid];
    int dst = ((((k14*16 + (n>>4))*10 + (kk>>5))*4 + ((kk>>3)&3))*16 + (n&15))*8 + (kk&7);
    W1T[dst] = (_Float16)v;
}

// XOR-swizzled LDS layout for X segments:
//   half element (row, k) lives at  row*STRIDE + ((k>>3) ^ (row&7))*8 + (k&7)
//   (STRIDE = 128 halves for g/h, 64 for ex).  Swizzle permutes 16B chunks
//   within each row, so b128 reads across rows spread evenly over banks.
__global__ __launch_bounds__(512, 4) void hopping_main(
    const float* __restrict__ sfeat, const float* __restrict__ pfeat,
    const float* __restrict__ dfeat, const float* __restrict__ Sfeat,
    const int*  __restrict__ hop,   const float* __restrict__ darr,
    const float* __restrict__ exd,  const float* __restrict__ b1,
    const float* __restrict__ W2,   const float* __restrict__ b2,
    const _Float16* __restrict__ W1T, float* __restrict__ out)
{
    // 3 rotating g/h buffers (16 KB each) + ex (8 KB) + reduction (4 KB) = 60.75 KB
    __shared__ _Float16 xbuf[3][64*128];
    __shared__ _Float16 exseg[64*64];
    __shared__ float    redbuf[2][8][64];
    __shared__ int      la1[64];
    __shared__ int      la2[64];
    __shared__ float    linv[64];

    const int  tid = threadIdx.x;           // 0..511
    const long e0  = (long)blockIdx.x * 64;

    if (tid < 64) {
        long eg = e0 + tid; if (eg >= NEDGE) eg = NEDGE - 1;
        la1[tid] = hop[2*eg];
        la2[tid] = hop[2*eg + 1];
        float dv = darr[eg];
        linv[tid] = 1.0f / (dv * dv);
    }

    const int ser = tid >> 3;   // staging row 0..63 (8 threads per row)
    const int sq  = tid & 7;

    // ex_d gather (no scaling), once per block
    {
        long eg = e0 + ser; if (eg >= NEDGE) eg = NEDGE - 1;
        const float4* src = (const float4*)exd + eg * 16;
        #pragma unroll
        for (int r = 0; r < 2; ++r) {
            int c8 = r*8 + sq;
            float4 v = src[c8];
            v4h hv; hv[0]=(_Float16)v.x; hv[1]=(_Float16)v.y;
                    hv[2]=(_Float16)v.z; hv[3]=(_Float16)v.w;
            *(v4h*)&exseg[ser*64 + (((c8>>1) ^ (ser&7))<<3) + (c8&1)*4] = hv;
        }
    }
    __syncthreads();   // la1/la2/linv visible

    // step-0 segments: pair (0,0) -> g = sfeat[la1], h = sfeat[la2]
    {
        float inv = linv[ser];
        const float4* srcg = (const float4*)sfeat + (size_t)la1[ser] * 32;
        const float4* srch = (const float4*)sfeat + (size_t)la2[ser] * 32;
        #pragma unroll
        for (int r = 0; r < 4; ++r) {
            int c8 = r*8 + sq;
            int di = ser*128 + (((c8>>1) ^ (ser&7))<<3) + (c8&1)*4;
            float4 v = srcg[c8];
            v4h hv; hv[0]=(_Float16)(v.x*inv); hv[1]=(_Float16)(v.y*inv);
                    hv[2]=(_Float16)(v.z*inv); hv[3]=(_Float16)(v.w*inv);
            *(v4h*)&xbuf[0][di] = hv;
            float4 u = srch[c8];
            v4h hu; hu[0]=(_Float16)(u.x*inv); hu[1]=(_Float16)(u.y*inv);
                    hu[2]=(_Float16)(u.z*inv); hu[3]=(_Float16)(u.w*inv);
            *(v4h*)&xbuf[1][di] = hu;
        }
    }
    __syncthreads();

    const int lane = tid & 63;
    const int w    = tid >> 6;      // wave 0..7 = N-split index
    const int col  = lane & 15;
    const int quad = lane >> 4;

    int off_g = 0, off_h = 1, off_sp = 2;

    #pragma unroll 1
    for (int step = 0; step < 14; ++step) {
        const int k14 = cK[step];

        // ---- T14: issue next step's gather into registers (latency hides
        //      under this step's MFMA loop); written to spare buffer later ----
        int stage_mode = 0;   // 0 none, 1 g, 2 h  (uniform across block)
        if (step < 13) {
            if (cLG[step+1])      stage_mode = 1;
            else if (cLH[step+1]) stage_mode = 2;
        }
        float4 st0, st1, st2, st3; float stinv = 0.f;
        if (stage_mode) {
            int t = (stage_mode == 1) ? cI[step+1] : cJ[step+1];
            const float* tab = (t==0)?sfeat:(t==1)?pfeat:(t==2)?dfeat:Sfeat;
            int arow = (stage_mode == 1) ? la1[ser] : la2[ser];
            const float4* src = (const float4*)tab + (size_t)arow * 32;
            stinv = linv[ser];
            st0 = src[sq]; st1 = src[8+sq]; st2 = src[16+sq]; st3 = src[24+sq];
        }

        // bias / W2 for this step's columns
        float b1v[2], w2v[2];
        #pragma unroll
        for (int nt = 0; nt < 2; ++nt) {
            int n = (w*2 + nt)*16 + col;
            b1v[nt] = b1[k14*256 + n];
            w2v[nt] = W2[k14*256 + n];
        }

        // ---- GEMM: H(64x256) = X(64x320) @ W1[k14], wave owns all M, 32 cols ----
        v4f acc[4][2];
        #pragma unroll
        for (int a = 0; a < 4; ++a) {
            acc[a][0] = (v4f){0.f,0.f,0.f,0.f};
            acc[a][1] = (v4f){0.f,0.f,0.f,0.f};
        }

        const _Float16* __restrict__ wb = W1T + (size_t)k14 * 81920;
        const _Float16* gb = &xbuf[off_g][0];
        const _Float16* hb = &xbuf[off_h][0];

        #pragma unroll
        for (int kc = 0; kc < 10; ++kc) {
            v8h af[4];
            #pragma unroll
            for (int mt = 0; mt < 4; ++mt) {
                int row = mt*16 + col;
                if (kc < 8) {
                    const _Float16* sb = (kc < 4) ? gb : hb;
                    int ck = (kc & 3)*4 + quad;
                    af[mt] = *(const v8h*)&sb[row*128 + ((ck ^ (row & 7))<<3)];
                } else {
                    int ck = (kc - 8)*4 + quad;
                    af[mt] = *(const v8h*)&exseg[row*64 + ((ck ^ (row & 7))<<3)];
                }
            }
            v8h bfr[2];
            #pragma unroll
            for (int nt = 0; nt < 2; ++nt)
                bfr[nt] = *(const v8h*)&wb[(((size_t)(w*2+nt)*10 + kc)*64 + lane)*8];
            #pragma unroll
            for (int mt = 0; mt < 4; ++mt)
                #pragma unroll
                for (int nt = 0; nt < 2; ++nt)
                    acc[mt][nt] = __builtin_amdgcn_mfma_f32_16x16x32_f16(
                        af[mt], bfr[nt], acc[mt][nt], 0, 0, 0);
        }

        // ---- epilogue: bias + leaky-relu + dot W2, reduce over 32 cols ----
        float p[4][4];
        #pragma unroll
        for (int mt = 0; mt < 4; ++mt)
            #pragma unroll
            for (int r = 0; r < 4; ++r) p[mt][r] = 0.f;
        #pragma unroll
        for (int nt = 0; nt < 2; ++nt)
            #pragma unroll
            for (int mt = 0; mt < 4; ++mt)
                #pragma unroll
                for (int r = 0; r < 4; ++r) {
                    float hv = acc[mt][nt][r] + b1v[nt];
                    hv = (hv > 0.f) ? hv : 0.01f * hv;
                    p[mt][r] += hv * w2v[nt];
                }
        #pragma unroll
        for (int mt = 0; mt < 4; ++mt)
            #pragma unroll
            for (int r = 0; r < 4; ++r) {
                float v = p[mt][r];
                v += __shfl_xor(v, 1, 16);
                v += __shfl_xor(v, 2, 16);
                v += __shfl_xor(v, 4, 16);
                v += __shfl_xor(v, 8, 16);
                if (col == 0) redbuf[step & 1][w][mt*16 + quad*4 + r] = v;
            }

        // ---- write staged gather into spare buffer (spare is not read
        //      this step; its last readers finished before previous barrier) ----
        if (stage_mode) {
            _Float16* dst = &xbuf[off_sp][0];
            #pragma unroll
            for (int r = 0; r < 4; ++r) {
                float4 v = (r==0) ? st0 : (r==1) ? st1 : (r==2) ? st2 : st3;
                int c8 = r*8 + sq;
                v4h hv; hv[0]=(_Float16)(v.x*stinv); hv[1]=(_Float16)(v.y*stinv);
                        hv[2]=(_Float16)(v.z*stinv); hv[3]=(_Float16)(v.w*stinv);
                *(v4h*)&dst[ser*128 + (((c8>>1) ^ (ser&7))<<3) + (c8&1)*4] = hv;
            }
        }

        __syncthreads();   // the ONLY barrier per step

        // ---- cross-wave reduction + store, rotating responsible wave ----
        if (w == (step & 7)) {
            long eg = e0 + lane;
            if (eg < NEDGE) {
                float v = b2[k14];
                #pragma unroll
                for (int ww = 0; ww < 8; ++ww) v += redbuf[step & 1][ww][lane];
                out[eg*14 + k14] = v;
            }
        }

        // rotate buffers for next step
        if (stage_mode == 1)      { int t = off_g; off_g = off_sp; off_sp = t; }
        else if (stage_mode == 2) { int t = off_h; off_h = off_sp; off_sp = t; }
    }
}

extern "C" void kernel_launch(void* const* d_in, const int* in_sizes, int n_in,
                              void* d_out, int out_size, void* d_ws, size_t ws_size,
                              hipStream_t stream)
{
    (void)in_sizes; (void)n_in; (void)out_size; (void)ws_size;
    const float* sfeat = (const float*)d_in[0];
    const float* pfeat = (const float*)d_in[1];
    const float* dfeat = (const float*)d_in[2];
    const float* Sfeat = (const float*)d_in[3];
    const int*   hop   = (const int*)  d_in[4];
    const float* darr  = (const float*)d_in[5];
    const float* exd   = (const float*)d_in[6];
    const float* W1    = (const float*)d_in[7];
    const float* b1    = (const float*)d_in[8];
    const float* W2    = (const float*)d_in[9];
    const float* b2    = (const float*)d_in[10];
    _Float16* W1T = (_Float16*)d_ws;   // 14*320*256*2 B = 2.29 MB

    // d_ws is re-poisoned before every timed call -> rebuild W1T every launch.
    prep_w1<<<dim3(4480), dim3(256), 0, stream>>>(W1, W1T);

    int nblk = (NEDGE + 63) / 64;   // 7813
    hopping_main<<<dim3(nblk), dim3(512), 0, stream>>>(
        sfeat, pfeat, dfeat, Sfeat, hop, darr, exd, b1, W2, b2, W1T, (float*)d_out);
}

// Round 3
// 2529.687 us; speedup vs baseline: 1.0717x; 1.0717x over previous
//
#include <hip/hip_runtime.h>

#define NEDGE  500000
#define NTILE  7813        // ceil(NEDGE/64)
#define NCH    280         // chunks (divisible by 8 XCDs: 35 per XCD)
#define CHUNK  28          // tiles per chunk; 280*28 = 7840 >= 7813
#define NPAIR  14

typedef _Float16 v8h __attribute__((ext_vector_type(8)));
typedef _Float16 v4h __attribute__((ext_vector_type(4)));
typedef float    v4f __attribute__((ext_vector_type(4)));

// PAIRS in natural k order: (0,0)(0,1)(1,1)(1,1)(0,2)(1,2)(1,2)(2,2)(2,2)(2,2)(3,3)(3,0)(3,1)(3,2)
__constant__ int cI[14] = {0,0,1,1,0,1,1,2,2,2,3,3,3,3};
__constant__ int cJ[14] = {0,1,1,1,2,2,2,2,2,2,3,0,1,2};

// W1 (14,320,256) fp32 -> W1T fp16 in MFMA-B-fragment tile order:
// W1T[k14][nt(16)][kc(10)][quad(4)][col(16)][j(8)]
//   element = W1[k14][kc*32+quad*8+j][nt*16+col]
__global__ __launch_bounds__(256) void prep_w1(const float* __restrict__ W1,
                                               _Float16* __restrict__ W1T) {
    int tid = blockIdx.x * 256 + threadIdx.x;
    if (tid >= 14*320*256) return;
    int n   = tid & 255;
    int t   = tid >> 8;
    int kk  = t % 320;
    int k14 = t / 320;
    float v = W1[tid];
    int dst = ((((k14*16 + (n>>4))*10 + (kk>>5))*4 + ((kk>>3)&3))*16 + (n&15))*8 + (kk&7);
    W1T[dst] = (_Float16)v;
}

// Weight-stationary main kernel: one k14 per block, CHUNK edge-tiles each.
// X buffer [64 rows][320 k] fp16, XOR-swizzled in 16B chunks within each
// 8-chunk group: chunk' = (ch & ~7) | ((ch ^ row) & 7)  (bijective per row,
// spreads the 16-rows-same-chunk b128 read pattern across 8 bank-quads).
__global__ __launch_bounds__(512) void hopping_ws(
    const float* __restrict__ sfeat, const float* __restrict__ pfeat,
    const float* __restrict__ dfeat, const float* __restrict__ Sfeat,
    const int*  __restrict__ hop,   const float* __restrict__ darr,
    const float* __restrict__ exd,  const float* __restrict__ b1,
    const float* __restrict__ W2,   const float* __restrict__ b2,
    const _Float16* __restrict__ W1T, float* __restrict__ out)
{
    __shared__ __attribute__((aligned(16))) _Float16 xbuf[64*320];   // 40 KB
    __shared__ float redbuf[2][8][64];                               //  4 KB

    const int tid = threadIdx.x;          // 0..511
    const int bid = blockIdx.x;           // 0..3919

    // XCD-aware mapping: bid%8 = XCD (round-robin assumption, perf-only).
    // Each XCD gets 35 contiguous chunks; the 14 k14-blocks of one chunk are
    // consecutive within the XCD -> co-resident -> shared gathers in its L2.
    const int xcd   = bid & 7;
    const int q     = bid >> 3;           // 0..489 = 35 chunks * 14 k14
    const int k14   = q % 14;
    const int chunk = xcd*35 + q/14;      // 0..279
    const long t0   = (long)chunk * CHUNK;
    int my_n = CHUNK;
    if (t0 + my_n > NTILE) my_n = (int)(NTILE - t0);
    if (my_n <= 0) return;

    const int i4 = cI[k14], j4 = cJ[k14];
    const float* gt = (i4==0)?sfeat:(i4==1)?pfeat:(i4==2)?dfeat:Sfeat;
    const float* ht = (j4==0)?sfeat:(j4==1)?pfeat:(j4==2)?dfeat:Sfeat;

    const int lane = tid & 63;
    const int w    = tid >> 6;            // wave 0..7: owns cols [w*32, w*32+32)
    const int col  = lane & 15;
    const int quad = lane >> 4;
    const int ser  = tid >> 3;            // staging row 0..63
    const int sq   = tid & 7;             // 8 threads per row

    // ---- resident B fragments: 2 nt x 10 kc x b128 = 80 VGPRs, loaded once ----
    v8h bfr[2][10];
    {
        const _Float16* wb = W1T + (size_t)k14 * 81920;
        #pragma unroll
        for (int nt = 0; nt < 2; ++nt)
            #pragma unroll
            for (int kc = 0; kc < 10; ++kc)
                bfr[nt][kc] = *(const v8h*)&wb[(((size_t)(w*2+nt)*10 + kc)*64 + lane)*8];
    }
    float b1v[2], w2v[2];
    #pragma unroll
    for (int nt = 0; nt < 2; ++nt) {
        int n = (w*2+nt)*16 + col;
        b1v[nt] = b1[k14*256 + n];
        w2v[nt] = W2[k14*256 + n];
    }
    const float b2v = b2[k14];

    // ---- T14 staging state (raw f32 in regs; convert at write time) ----
    float4 sg[4], sh[4], sx[2]; float sinv = 0.f;

    auto stage_load = [&](int ti) {
        long eg = (t0 + ti)*64 + ser;
        if (eg >= NEDGE) eg = NEDGE - 1;
        int a1 = hop[2*eg];
        int a2 = hop[2*eg + 1];
        float dv = darr[eg];
        sinv = 1.0f / (dv * dv);
        const float4* s1 = (const float4*)gt + (size_t)a1 * 32;
        const float4* s2 = (const float4*)ht + (size_t)a2 * 32;
        #pragma unroll
        for (int r = 0; r < 4; ++r) { sg[r] = s1[r*8 + sq]; sh[r] = s2[r*8 + sq]; }
        const float4* s3 = (const float4*)exd + eg * 16;
        sx[0] = s3[sq]; sx[1] = s3[8 + sq];
    };

    auto stage_write = [&]() {
        #pragma unroll
        for (int r = 0; r < 4; ++r) {
            int c  = r*8 + sq;            // f32 float4 index 0..31 within row
            int ch = c >> 1;              // g chunks 0..15
            int sz1 = (ch & ~7) | ((ch ^ ser) & 7);
            v4h hv; hv[0]=(_Float16)(sg[r].x*sinv); hv[1]=(_Float16)(sg[r].y*sinv);
                    hv[2]=(_Float16)(sg[r].z*sinv); hv[3]=(_Float16)(sg[r].w*sinv);
            *(v4h*)&xbuf[ser*320 + sz1*8 + (c&1)*4] = hv;
            int ch2 = 16 + ch;            // h chunks 16..31
            int sz2 = (ch2 & ~7) | ((ch2 ^ ser) & 7);
            v4h hu; hu[0]=(_Float16)(sh[r].x*sinv); hu[1]=(_Float16)(sh[r].y*sinv);
                    hu[2]=(_Float16)(sh[r].z*sinv); hu[3]=(_Float16)(sh[r].w*sinv);
            *(v4h*)&xbuf[ser*320 + sz2*8 + (c&1)*4] = hu;
        }
        #pragma unroll
        for (int r = 0; r < 2; ++r) {
            int c  = r*8 + sq;            // ex float4 index 0..15
            int ch = 32 + (c >> 1);       // ex chunks 32..39
            int sz = (ch & ~7) | ((ch ^ ser) & 7);
            v4h hv; hv[0]=(_Float16)sx[r].x; hv[1]=(_Float16)sx[r].y;
                    hv[2]=(_Float16)sx[r].z; hv[3]=(_Float16)sx[r].w;
            *(v4h*)&xbuf[ser*320 + sz*8 + (c&1)*4] = hv;
        }
    };

    stage_load(0);
    stage_write();
    __syncthreads();

    #pragma unroll 1
    for (int ti = 0; ti < my_n; ++ti) {
        const bool have_next = (ti + 1 < my_n);
        if (have_next) stage_load(ti + 1);   // global loads in flight under MFMA

        v4f acc[4][2];
        #pragma unroll
        for (int a = 0; a < 4; ++a) {
            acc[a][0] = (v4f){0.f,0.f,0.f,0.f};
            acc[a][1] = (v4f){0.f,0.f,0.f,0.f};
        }

        #pragma unroll
        for (int kc = 0; kc < 10; ++kc) {
            v8h af[4];
            #pragma unroll
            for (int mt = 0; mt < 4; ++mt) {
                int row = mt*16 + col;
                int ck  = kc*4 + quad;                 // chunk 0..39
                int sz  = (ck & ~7) | ((ck ^ row) & 7);
                af[mt] = *(const v8h*)&xbuf[row*320 + sz*8];
            }
            #pragma unroll
            for (int mt = 0; mt < 4; ++mt)
                #pragma unroll
                for (int nt = 0; nt < 2; ++nt)
                    acc[mt][nt] = __builtin_amdgcn_mfma_f32_16x16x32_f16(
                        af[mt], bfr[nt][kc], acc[mt][nt], 0, 0, 0);
        }

        // ---- epilogue: bias + leaky-relu + dot W2, reduce over this wave's 32 cols ----
        float p[4][4];
        #pragma unroll
        for (int mt = 0; mt < 4; ++mt)
            #pragma unroll
            for (int r = 0; r < 4; ++r) p[mt][r] = 0.f;
        #pragma unroll
        for (int nt = 0; nt < 2; ++nt)
            #pragma unroll
            for (int mt = 0; mt < 4; ++mt)
                #pragma unroll
                for (int r = 0; r < 4; ++r) {
                    float hv = acc[mt][nt][r] + b1v[nt];
                    hv = (hv > 0.f) ? hv : 0.01f * hv;
                    p[mt][r] += hv * w2v[nt];
                }
        #pragma unroll
        for (int mt = 0; mt < 4; ++mt)
            #pragma unroll
            for (int r = 0; r < 4; ++r) {
                float v = p[mt][r];
                v += __shfl_xor(v, 1, 16);
                v += __shfl_xor(v, 2, 16);
                v += __shfl_xor(v, 4, 16);
                v += __shfl_xor(v, 8, 16);
                if (col == 0) redbuf[ti & 1][w][mt*16 + quad*4 + r] = v;
            }

        __syncthreads();   // A: xbuf reads done + redbuf visible

        if (have_next) stage_write();        // short: cvt+mul+ds_write only

        if (w == (ti & 7)) {                 // rotating reducer wave
            long eg = (t0 + ti)*64 + lane;
            if (eg < NEDGE) {
                float v = b2v;
                #pragma unroll
                for (int ww = 0; ww < 8; ++ww) v += redbuf[ti & 1][ww][lane];
                out[eg*14 + k14] = v;
            }
        }

        __syncthreads();   // B: xbuf writes visible for next tile
    }
}

extern "C" void kernel_launch(void* const* d_in, const int* in_sizes, int n_in,
                              void* d_out, int out_size, void* d_ws, size_t ws_size,
                              hipStream_t stream)
{
    (void)in_sizes; (void)n_in; (void)out_size; (void)ws_size;
    const float* sfeat = (const float*)d_in[0];
    const float* pfeat = (const float*)d_in[1];
    const float* dfeat = (const float*)d_in[2];
    const float* Sfeat = (const float*)d_in[3];
    const int*   hop   = (const int*)  d_in[4];
    const float* darr  = (const float*)d_in[5];
    const float* exd   = (const float*)d_in[6];
    const float* W1    = (const float*)d_in[7];
    const float* b1    = (const float*)d_in[8];
    const float* W2    = (const float*)d_in[9];
    const float* b2    = (const float*)d_in[10];
    _Float16* W1T = (_Float16*)d_ws;   // 14*320*256*2 B = 2.29 MB

    // d_ws is re-poisoned before every timed call -> rebuild W1T every launch.
    prep_w1<<<dim3(4480), dim3(256), 0, stream>>>(W1, W1T);

    // 280 chunks x 14 k14 = 3920 blocks, XCD-grouped ordering baked into kernel.
    hopping_ws<<<dim3(NCH * NPAIR), dim3(512), 0, stream>>>(
        sfeat, pfeat, dfeat, Sfeat, hop, darr, exd, b1, W2, b2, W1T, (float*)d_out);
}

// Round 4
// 1538.656 us; speedup vs baseline: 1.7620x; 1.6441x over previous
//
#include <hip/hip_runtime.h>

#define NEDGE  500000
#define NTILE  7813        // ceil(NEDGE/64)
#define NCH    280         // chunks (divisible by 8 XCDs: 35 per XCD)
#define CHUNK  28          // tiles per chunk; 280*28 = 7840 >= 7813
#define NPAIR  14

typedef _Float16 v8h __attribute__((ext_vector_type(8)));
typedef _Float16 v4h __attribute__((ext_vector_type(4)));
typedef float    v4f __attribute__((ext_vector_type(4)));

// PAIRS in natural k order
__constant__ int cI[14] = {0,0,1,1,0,1,1,2,2,2,3,3,3,3};
__constant__ int cJ[14] = {0,1,1,1,2,2,2,2,2,2,3,0,1,2};

// W1 (14,320,256) fp32 -> W1T fp16 in MFMA-B-fragment tile order:
// W1T[k14][nt(16)][kc(10)][quad(4)][col(16)][j(8)]
__global__ __launch_bounds__(256) void prep_w1(const float* __restrict__ W1,
                                               _Float16* __restrict__ W1T) {
    int tid = blockIdx.x * 256 + threadIdx.x;
    if (tid >= 14*320*256) return;
    int n   = tid & 255;
    int t   = tid >> 8;
    int kk  = t % 320;
    int k14 = t / 320;
    float v = W1[tid];
    int dst = ((((k14*16 + (n>>4))*10 + (kk>>5))*4 + ((kk>>3)&3))*16 + (n&15))*8 + (kk&7);
    W1T[dst] = (_Float16)v;
}

// Dynamic LDS layout (bytes):
//   [     0,  81920)  xbuf[2][64*320] f16  (double-buffered X tile, swizzled)
//   [ 81920, 147456)  part[2][128*16*4] f32 (parity-buffered reduction scratch)
// X swizzle: 16B chunk ck at row -> ck' = (ck & ~7) | ((ck ^ row) & 7)
// part addr: word = P*64 + Qx*4 + r,  P=w*16+col (0..127), Q=mt*4+quad,
//   Qx = Q ^ (P&7) ^ ((P>>4)&7)   (bank-balanced for both write and read)
__global__ __launch_bounds__(512, 2) void hopping_ws(
    const float* __restrict__ sfeat, const float* __restrict__ pfeat,
    const float* __restrict__ dfeat, const float* __restrict__ Sfeat,
    const int*  __restrict__ hop,   const float* __restrict__ darr,
    const float* __restrict__ exd,  const float* __restrict__ b1,
    const float* __restrict__ W2,   const float* __restrict__ b2,
    const _Float16* __restrict__ W1T, float* __restrict__ out)
{
    extern __shared__ char smem[];
    _Float16* xb0  = (_Float16*)smem;                 // 2 x 20480 halves
    float*    part = (float*)(smem + 81920);          // 2 x 8192 floats

    const int tid = threadIdx.x;          // 0..511
    const int bid = blockIdx.x;           // 0..3919

    const int xcd   = bid & 7;
    const int q     = bid >> 3;
    const int k14   = q % 14;
    const int chunk = xcd*35 + q/14;      // 0..279
    const long t0   = (long)chunk * CHUNK;
    int my_n = CHUNK;
    if (t0 + my_n > NTILE) my_n = (int)(NTILE - t0);   // always >= 1

    const int i4 = cI[k14], j4 = cJ[k14];
    const float* gt = (i4==0)?sfeat:(i4==1)?pfeat:(i4==2)?dfeat:Sfeat;
    const float* ht = (j4==0)?sfeat:(j4==1)?pfeat:(j4==2)?dfeat:Sfeat;

    const int lane = tid & 63;
    const int w    = tid >> 6;            // wave 0..7: owns cols [w*32, w*32+32)
    const int col  = lane & 15;
    const int quad = lane >> 4;
    const int ser  = tid >> 3;            // staging row 0..63
    const int sq   = tid & 7;             // 8 threads per row

    // ---- resident B fragments: 2 nt x 10 kc x b128 = 80 VGPRs, loaded once ----
    v8h bfr[2][10];
    {
        const _Float16* wb = W1T + (size_t)k14 * 81920;
        #pragma unroll
        for (int nt = 0; nt < 2; ++nt)
            #pragma unroll
            for (int kc = 0; kc < 10; ++kc)
                bfr[nt][kc] = *(const v8h*)&wb[(((size_t)(w*2+nt)*10 + kc)*64 + lane)*8];
    }
    float b1v[2], w2v[2];
    #pragma unroll
    for (int nt = 0; nt < 2; ++nt) {
        int n = (w*2+nt)*16 + col;
        b1v[nt] = b1[k14*256 + n];
        w2v[nt] = W2[k14*256 + n];
    }
    const float b2v = b2[k14];

    // ---- staging state ----
    float4 sg[4], sh[4], sx[2]; float sinv = 0.f;

    auto hopload = [&](int ti, int& a1, int& a2, float& dv) {
        long eg = (t0 + ti)*64 + ser; if (eg >= NEDGE) eg = NEDGE - 1;
        a1 = hop[2*eg]; a2 = hop[2*eg + 1]; dv = darr[eg];
    };
    auto gather_issue = [&](int ti, int a1, int a2, float dv) {
        sinv = 1.0f / (dv * dv);
        const float4* s1 = (const float4*)gt + (size_t)a1 * 32;
        const float4* s2 = (const float4*)ht + (size_t)a2 * 32;
        #pragma unroll
        for (int r = 0; r < 4; ++r) { sg[r] = s1[r*8 + sq]; sh[r] = s2[r*8 + sq]; }
        long eg = (t0 + ti)*64 + ser; if (eg >= NEDGE) eg = NEDGE - 1;
        const float4* s3 = (const float4*)exd + eg * 16;
        sx[0] = s3[sq]; sx[1] = s3[8 + sq];
    };
    auto stage_write = [&](_Float16* dst) {
        #pragma unroll
        for (int r = 0; r < 4; ++r) {
            int c  = r*8 + sq;            // f32 float4 index 0..31 within row
            int ch = c >> 1;              // g chunks 0..15
            int sz1 = (ch & ~7) | ((ch ^ ser) & 7);
            v4h hv; hv[0]=(_Float16)(sg[r].x*sinv); hv[1]=(_Float16)(sg[r].y*sinv);
                    hv[2]=(_Float16)(sg[r].z*sinv); hv[3]=(_Float16)(sg[r].w*sinv);
            *(v4h*)&dst[ser*320 + sz1*8 + (c&1)*4] = hv;
            int ch2 = 16 + ch;            // h chunks 16..31
            int sz2 = (ch2 & ~7) | ((ch2 ^ ser) & 7);
            v4h hu; hu[0]=(_Float16)(sh[r].x*sinv); hu[1]=(_Float16)(sh[r].y*sinv);
                    hu[2]=(_Float16)(sh[r].z*sinv); hu[3]=(_Float16)(sh[r].w*sinv);
            *(v4h*)&dst[ser*320 + sz2*8 + (c&1)*4] = hu;
        }
        #pragma unroll
        for (int r = 0; r < 2; ++r) {
            int c  = r*8 + sq;            // ex float4 index 0..15
            int ch = 32 + (c >> 1);       // ex chunks 32..39
            int sz = (ch & ~7) | ((ch ^ ser) & 7);
            v4h hv; hv[0]=(_Float16)sx[r].x; hv[1]=(_Float16)sx[r].y;
                    hv[2]=(_Float16)sx[r].z; hv[3]=(_Float16)sx[r].w;
            *(v4h*)&dst[ser*320 + sz*8 + (c&1)*4] = hv;
        }
    };

    // ---- prologue: fill buffer 0 for tile 0; prefetch hop for tile 1 ----
    int ca1, ca2; float cdv;      // hop data for tile (ti+1), ready
    int fa1, fa2; float fdv;      // hop data for tile (ti+2), in flight
    {
        int a1, a2; float dv;
        hopload(0, a1, a2, dv);
        gather_issue(0, a1, a2, dv);     // exposed once per block
        hopload(1, ca1, ca2, cdv);
        stage_write(xb0);
    }
    __syncthreads();

    #pragma unroll 1
    for (int ti = 0; ti < my_n; ++ti) {
        const int  cur = ti & 1;
        const bool hn  = (ti + 1 < my_n);

        // 1. issue next tile's gathers (addresses already in regs) + hop(ti+2)
        if (hn)              gather_issue(ti+1, ca1, ca2, cdv);
        if (ti + 2 < my_n)   hopload(ti+2, fa1, fa2, fdv);

        // 2. GEMM over current buffer
        const _Float16* xb = xb0 + cur*20480;
        v4f acc[4][2];
        #pragma unroll
        for (int a = 0; a < 4; ++a) {
            acc[a][0] = (v4f){0.f,0.f,0.f,0.f};
            acc[a][1] = (v4f){0.f,0.f,0.f,0.f};
        }
        #pragma unroll
        for (int kc = 0; kc < 10; ++kc) {
            v8h af[4];
            #pragma unroll
            for (int mt = 0; mt < 4; ++mt) {
                int row = mt*16 + col;
                int ck  = kc*4 + quad;
                int sz  = (ck & ~7) | ((ck ^ row) & 7);
                af[mt] = *(const v8h*)&xb[row*320 + sz*8];
            }
            #pragma unroll
            for (int mt = 0; mt < 4; ++mt)
                #pragma unroll
                for (int nt = 0; nt < 2; ++nt)
                    acc[mt][nt] = __builtin_amdgcn_mfma_f32_16x16x32_f16(
                        af[mt], bfr[nt][kc], acc[mt][nt], 0, 0, 0);
        }

        // 3. epilogue: bias + leaky-relu + dot W2 (partial over this lane's 2 cols)
        //    -> write v4f partials to part[cur] (conflict-balanced layout)
        {
            float* pb = part + cur*8192;
            #pragma unroll
            for (int mt = 0; mt < 4; ++mt) {
                v4f pv = (v4f){0.f,0.f,0.f,0.f};
                #pragma unroll
                for (int nt = 0; nt < 2; ++nt)
                    #pragma unroll
                    for (int r = 0; r < 4; ++r) {
                        float hv = acc[mt][nt][r] + b1v[nt];
                        hv = (hv > 0.f) ? hv : 0.01f * hv;
                        pv[r] += hv * w2v[nt];
                    }
                int P  = w*16 + col;
                int Qx = (mt*4 + quad) ^ (col & 7) ^ w;
                *(v4f*)&pb[P*64 + Qx*4] = pv;
            }
        }

        // 4. write staged gathers into the other buffer (its readers finished
        //    before the PREVIOUS barrier)
        if (hn) stage_write(xb0 + (cur^1)*20480);

        __syncthreads();   // the ONLY barrier per tile

        // 5. reduction of part[cur]: 512 threads = 64 rows x 8 segs
        {
            const float* pr = part + cur*8192;
            int row = tid >> 3, seg = tid & 7;
            int Q = row >> 2, r = row & 3;
            float v = 0.f;
            #pragma unroll
            for (int i = 0; i < 16; ++i) {
                int P  = seg*16 + i;
                int Qx = Q ^ (i & 7) ^ seg;
                v += pr[P*64 + Qx*4 + r];
            }
            v += __shfl_xor(v, 1, 8);
            v += __shfl_xor(v, 2, 8);
            v += __shfl_xor(v, 4, 8);
            if (seg == 0) {
                long eg = (t0 + ti)*64 + row;
                if (eg < NEDGE) out[eg*14 + k14] = v + b2v;
            }
        }

        // rotate hop prefetch regs (waitcnt lands here, ~1 tile of slack)
        ca1 = fa1; ca2 = fa2; cdv = fdv;
    }
}

extern "C" void kernel_launch(void* const* d_in, const int* in_sizes, int n_in,
                              void* d_out, int out_size, void* d_ws, size_t ws_size,
                              hipStream_t stream)
{
    (void)in_sizes; (void)n_in; (void)out_size; (void)ws_size;
    const float* sfeat = (const float*)d_in[0];
    const float* pfeat = (const float*)d_in[1];
    const float* dfeat = (const float*)d_in[2];
    const float* Sfeat = (const float*)d_in[3];
    const int*   hop   = (const int*)  d_in[4];
    const float* darr  = (const float*)d_in[5];
    const float* exd   = (const float*)d_in[6];
    const float* W1    = (const float*)d_in[7];
    const float* b1    = (const float*)d_in[8];
    const float* W2    = (const float*)d_in[9];
    const float* b2    = (const float*)d_in[10];
    _Float16* W1T = (_Float16*)d_ws;   // 14*320*256*2 B = 2.29 MB

    static bool attr_done = false;
    if (!attr_done) {
        hipFuncSetAttribute((const void*)hopping_ws,
                            hipFuncAttributeMaxDynamicSharedMemorySize, 147456);
        attr_done = true;
    }

    // d_ws is re-poisoned before every timed call -> rebuild W1T every launch.
    prep_w1<<<dim3(4480), dim3(256), 0, stream>>>(W1, W1T);

    hopping_ws<<<dim3(NCH * NPAIR), dim3(512), 147456, stream>>>(
        sfeat, pfeat, dfeat, Sfeat, hop, darr, exd, b1, W2, b2, W1T, (float*)d_out);
}